// Round 1
// baseline (561.126 us; speedup 1.0000x reference)
//
#include <hip/hip_runtime.h>

typedef __bf16 bf16x8 __attribute__((ext_vector_type(8)));
typedef float f32x4 __attribute__((ext_vector_type(4)));
typedef unsigned short u16;
typedef unsigned int u32;

#define DEV static __device__ __forceinline__

DEV u16 f2bf(float f) {
  u32 u = __builtin_bit_cast(u32, f);
  u += 0x7fffu + ((u >> 16) & 1u);   // RNE (inputs are finite, no NaN handling)
  return (u16)(u >> 16);
}

DEV f32x4 mfma16(bf16x8 a, bf16x8 b, f32x4 c) {
  return __builtin_amdgcn_mfma_f32_16x16x32_bf16(a, b, c, 0, 0, 0);
}

DEV void gload16(const void* g, void* l) {
  __builtin_amdgcn_global_load_lds((const __attribute__((address_space(1))) u32*)g,
                                   (__attribute__((address_space(3))) u32*)l, 16, 0, 0);
}

// ---------------- pack weights: Wqkv (3072x1024 bf16), Wo (1024x1024 bf16), bqkv ----------------
__global__ void pack_w(const float* __restrict__ wq, const float* __restrict__ wk,
                       const float* __restrict__ wv, const float* __restrict__ wo,
                       const float* __restrict__ bq, const float* __restrict__ bk,
                       const float* __restrict__ bv,
                       u16* __restrict__ Wqkv, u16* __restrict__ Wo, float* __restrict__ bqkv) {
  const int i = blockIdx.x * 256 + threadIdx.x;
  if (i < 3145728) {
    const int n = i >> 10;
    const float* s = (n < 1024) ? wq : (n < 2048) ? wk : wv;
    Wqkv[i] = f2bf(s[(n & 1023) * 1024 + (i & 1023)]);
  } else if (i < 4194304) {
    Wo[i - 3145728] = f2bf(wo[i - 3145728]);
  } else if (i < 4197376) {
    const int j = i - 4194304;
    bqkv[j] = (j < 1024) ? bq[j] : (j < 2048) ? bk[j - 1024] : bv[j - 2048];
  }
}

// ---------------- x -> bf16 ----------------
__global__ void cvt_x(const float4* __restrict__ x, u16* __restrict__ xb) {
  const int i = blockIdx.x * 256 + threadIdx.x;   // exactly 2,097,152 threads
  float4 v = x[i];
  union { u16 h[4]; uint2 d; } r;
  r.h[0] = f2bf(v.x); r.h[1] = f2bf(v.y); r.h[2] = f2bf(v.z); r.h[3] = f2bf(v.w);
  *(uint2*)&xb[(size_t)i * 4] = r.d;
}

// ---------------- GEMM C = A * B^T (+bias), A: MxK bf16 row-major, B: NxK bf16 row-major ----------
// MODE 0: QKV epilogue -> Q,K (B,H,T,Dh) and V^T (B,H,Dh,T), bf16
// MODE 1: plain fp32 C (M x 1024) + bias
template<int MODE>
__global__ __launch_bounds__(256)
void gemm_bt(const u16* __restrict__ A, const u16* __restrict__ B,
             const float* __restrict__ bias, float* __restrict__ Cf,
             u16* __restrict__ Qs, u16* __restrict__ Ks, u16* __restrict__ Vts,
             int K) {
  __shared__ u16 Asm[128 * 32];
  __shared__ u16 Bsm[128 * 32];
  const int tid = threadIdx.x, lane = tid & 63, w = tid >> 6;
  const int tn = blockIdx.x, tm = blockIdx.y;
  const int wr = w >> 1, wc = w & 1;
  f32x4 acc[4][4] = {};
  const size_t Kb = (size_t)K * 2;
  const char* Ab = (const char*)A + (size_t)(tm * 128) * Kb;
  const char* Bb = (const char*)B + (size_t)(tn * 128) * Kb;
  const int c0 = w * 2, c1 = c0 + 1;
  // chunk c covers LDS bytes [c*1024, c*1024+1024): row = c*16 + lane/4, colbyte = (lane%4)*16
  const size_t soff0 = (size_t)(c0 * 16 + (lane >> 2)) * Kb + (size_t)(lane & 3) * 16;
  const size_t soff1 = (size_t)(c1 * 16 + (lane >> 2)) * Kb + (size_t)(lane & 3) * 16;
  u16* la0 = Asm + c0 * 512;  u16* la1 = Asm + c1 * 512;
  u16* lb0 = Bsm + c0 * 512;  u16* lb1 = Bsm + c1 * 512;
  const int ar = (wr * 64 + (lane & 15)) * 32 + (lane >> 4) * 8;
  const int br = (wc * 64 + (lane & 15)) * 32 + (lane >> 4) * 8;

  for (int kt = 0; kt < K; kt += 32) {
    if (kt) __syncthreads();
    gload16(Ab + soff0 + (size_t)kt * 2, la0);
    gload16(Ab + soff1 + (size_t)kt * 2, la1);
    gload16(Bb + soff0 + (size_t)kt * 2, lb0);
    gload16(Bb + soff1 + (size_t)kt * 2, lb1);
    __syncthreads();
    bf16x8 af[4], bfv[4];
#pragma unroll
    for (int mf = 0; mf < 4; mf++) af[mf] = *(const bf16x8*)&Asm[ar + mf * 512];
#pragma unroll
    for (int nf = 0; nf < 4; nf++) bfv[nf] = *(const bf16x8*)&Bsm[br + nf * 512];
#pragma unroll
    for (int mf = 0; mf < 4; mf++)
#pragma unroll
      for (int nf = 0; nf < 4; nf++)
        acc[mf][nf] = mfma16(af[mf], bfv[nf], acc[mf][nf]);
  }

  // epilogue: C row m = ... + (lane>>4)*4 + r, col n = ... + (lane&15)
  const int nbase = tn * 128 + wc * 64 + (lane & 15);
  const int mbase = tm * 128 + wr * 64 + (lane >> 4) * 4;
#pragma unroll
  for (int nf = 0; nf < 4; nf++) {
    const int n = nbase + nf * 16;
    const float bias_n = bias[n];
    if (MODE == 0) {
      const int sec = n >> 10;                 // 0=Q 1=K 2=V (tile cols never straddle)
      const int h = (n & 1023) >> 6, dh = n & 63;
#pragma unroll
      for (int mf = 0; mf < 4; mf++) {
#pragma unroll
        for (int r = 0; r < 4; r++) {
          const int m = mbase + mf * 16 + r;
          const int b = m >> 11, t = m & 2047;
          const size_t base = (size_t)(b * 16 + h) << 17;   // *131072
          const u16 val = f2bf(acc[mf][nf][r] + bias_n);
          if (sec == 0)      Qs[base + (size_t)t * 64 + dh] = val;
          else if (sec == 1) Ks[base + (size_t)t * 64 + dh] = val;
          else               Vts[base + (size_t)dh * 2048 + t] = val;
        }
      }
    } else {
#pragma unroll
      for (int mf = 0; mf < 4; mf++)
#pragma unroll
        for (int r = 0; r < 4; r++) {
          const int m = mbase + mf * 16 + r;
          Cf[(size_t)m * 1024 + n] = acc[mf][nf][r] + bias_n;
        }
    }
  }
}

// ---------------- causal flash attention ----------------
// grid: (T/128, B*H). block: 256 = 4 waves; wave owns 32 q-rows. KV blocks of 32 keys in LDS.
__global__ __launch_bounds__(256)
void attn_fwd(const u16* __restrict__ Qg, const u16* __restrict__ Kgl,
              const u16* __restrict__ Vgl, u16* __restrict__ AO) {
  __shared__ u16 Ksm[32 * 72];     // 32 keys x 64 dh, stride 72 (bank-conflict pad)
  __shared__ u16 Vsm[64 * 40];     // 64 dh x 32 keys (V^T), stride 40
  __shared__ u16 Pb[4][32 * 40];   // per-wave P transpose buffer
  const int tid = threadIdx.x, lane = tid & 63, w = tid >> 6;
  const int qt = blockIdx.x, bh = blockIdx.y;
  const int r0 = qt * 128 + w * 32;
  const size_t hb = (size_t)bh << 17;
  const int ln15 = lane & 15, lh = lane >> 4;

  bf16x8 qa[2][2];
#pragma unroll
  for (int rg = 0; rg < 2; rg++)
#pragma unroll
    for (int c = 0; c < 2; c++)
      qa[rg][c] = *(const bf16x8*)&Qg[hb + (size_t)(r0 + rg * 16 + ln15) * 64 + c * 32 + lh * 8];

  f32x4 o[2][4] = {};
  float mr[2][4], lr[2][4];
#pragma unroll
  for (int rg = 0; rg < 2; rg++)
#pragma unroll
    for (int r = 0; r < 4; r++) { mr[rg][r] = -3.0e38f; lr[rg][r] = 0.f; }

  const int kmax = qt * 128 + 96;                    // last kb needed by block
  const float SC = 0.18033688011112042f;             // log2(e) / sqrt(64)
  const int krow = tid >> 3, kcol = (tid & 7) * 8;
  const int vrow = tid >> 2, vcol = (tid & 3) * 8;
  const f32x4 zz = {0.f, 0.f, 0.f, 0.f};

  for (int kb = 0; kb <= kmax; kb += 32) {
    if (kb) __syncthreads();
    *(uint4*)&Ksm[krow * 72 + kcol] = *(const uint4*)&Kgl[hb + (size_t)(kb + krow) * 64 + kcol];
    *(uint4*)&Vsm[vrow * 40 + vcol] = *(const uint4*)&Vgl[hb + (size_t)vrow * 2048 + kb + vcol];
    __syncthreads();
    if (kb > r0 + 31) continue;    // fully-masked for this wave (uniform branch; barriers above)

    bf16x8 kf[2][2];
#pragma unroll
    for (int g = 0; g < 2; g++)
#pragma unroll
      for (int c = 0; c < 2; c++)
        kf[g][c] = *(const bf16x8*)&Ksm[(g * 16 + ln15) * 72 + c * 32 + lh * 8];

    float p[2][2][4];
#pragma unroll
    for (int rg = 0; rg < 2; rg++)
#pragma unroll
      for (int g = 0; g < 2; g++) {
        f32x4 s = mfma16(qa[rg][1], kf[g][1], mfma16(qa[rg][0], kf[g][0], zz));
#pragma unroll
        for (int r = 0; r < 4; r++) p[rg][g][r] = s[r] * SC;
      }

    if (kb + 31 > r0) {            // only diagonal blocks need masking
#pragma unroll
      for (int rg = 0; rg < 2; rg++)
#pragma unroll
        for (int g = 0; g < 2; g++) {
          const int key = kb + g * 16 + ln15;
#pragma unroll
          for (int r = 0; r < 4; r++) {
            const int qrow = r0 + rg * 16 + lh * 4 + r;
            if (key > qrow) p[rg][g][r] = -3.0e38f;
          }
        }
    }

#pragma unroll
    for (int rg = 0; rg < 2; rg++)
#pragma unroll
      for (int r = 0; r < 4; r++) {
        float mb = fmaxf(p[rg][0][r], p[rg][1][r]);
        mb = fmaxf(mb, __shfl_xor(mb, 1));
        mb = fmaxf(mb, __shfl_xor(mb, 2));
        mb = fmaxf(mb, __shfl_xor(mb, 4));
        mb = fmaxf(mb, __shfl_xor(mb, 8));
        const float mn = fmaxf(mr[rg][r], mb);
        const float al = exp2f(mr[rg][r] - mn);
        mr[rg][r] = mn;
        const float e0 = exp2f(p[rg][0][r] - mn);
        const float e1 = exp2f(p[rg][1][r] - mn);
        p[rg][0][r] = e0; p[rg][1][r] = e1;
        float rs = e0 + e1;
        rs += __shfl_xor(rs, 1);
        rs += __shfl_xor(rs, 2);
        rs += __shfl_xor(rs, 4);
        rs += __shfl_xor(rs, 8);
        lr[rg][r] = lr[rg][r] * al + rs;
#pragma unroll
        for (int dhb = 0; dhb < 4; dhb++) o[rg][dhb][r] *= al;
      }

    // P: C-layout (col=key=ln15, row=lh*4+r) -> LDS -> A-frag (row=ln15, k=lh*8..)
#pragma unroll
    for (int rg = 0; rg < 2; rg++)
#pragma unroll
      for (int g = 0; g < 2; g++)
#pragma unroll
        for (int r = 0; r < 4; r++)
          Pb[w][(rg * 16 + lh * 4 + r) * 40 + g * 16 + ln15] = f2bf(p[rg][g][r]);

    bf16x8 pa[2];
#pragma unroll
    for (int rg = 0; rg < 2; rg++)
      pa[rg] = *(const bf16x8*)&Pb[w][(rg * 16 + ln15) * 40 + lh * 8];
#pragma unroll
    for (int dhb = 0; dhb < 4; dhb++) {
      const bf16x8 vb = *(const bf16x8*)&Vsm[(dhb * 16 + ln15) * 40 + lh * 8];
#pragma unroll
      for (int rg = 0; rg < 2; rg++)
        o[rg][dhb] = mfma16(pa[rg], vb, o[rg][dhb]);
    }
  }

  const int b = bh >> 4, h = bh & 15;
#pragma unroll
  for (int rg = 0; rg < 2; rg++)
#pragma unroll
    for (int r = 0; r < 4; r++) {
      const float inv = 1.0f / lr[rg][r];
      const int qrow = r0 + rg * 16 + lh * 4 + r;
      const size_t rowb = (size_t)(b * 2048 + qrow) * 1024 + h * 64;
#pragma unroll
      for (int dhb = 0; dhb < 4; dhb++)
        AO[rowb + dhb * 16 + ln15] = f2bf(o[rg][dhb][r] * inv);
    }
}

extern "C" void kernel_launch(void* const* d_in, const int* in_sizes, int n_in,
                              void* d_out, int out_size, void* d_ws, size_t ws_size,
                              hipStream_t stream) {
  const float* x  = (const float*)d_in[0];
  const float* wq = (const float*)d_in[1];
  const float* bq = (const float*)d_in[2];
  const float* wk = (const float*)d_in[3];
  const float* bk = (const float*)d_in[4];
  const float* wv = (const float*)d_in[5];
  const float* bv = (const float*)d_in[6];
  const float* wo = (const float*)d_in[7];
  const float* bo = (const float*)d_in[8];

  char* p = (char*)d_ws;
  u16* xb    = (u16*)p;   p += 16777216;   // 8192x1024 bf16; reused as AO after GEMM1
  u16* Wqkv  = (u16*)p;   p += 6291456;    // 3072x1024 bf16
  u16* Wo    = (u16*)p;   p += 2097152;    // 1024x1024 bf16
  float* bqkv = (float*)p; p += 12288;     // 3072 fp32
  u16* Qs    = (u16*)p;   p += 16777216;   // (B,H,T,Dh) bf16
  u16* Ks    = (u16*)p;   p += 16777216;   // (B,H,T,Dh) bf16
  u16* Vts   = (u16*)p;   p += 16777216;   // (B,H,Dh,T) bf16
  u16* AO    = xb;                         // attention output (B,T,H*Dh) bf16 — aliases xb

  pack_w<<<16396, 256, 0, stream>>>(wq, wk, wv, wo, bq, bk, bv, Wqkv, Wo, bqkv);
  cvt_x<<<8192, 256, 0, stream>>>((const float4*)x, xb);
  gemm_bt<0><<<dim3(24, 64), 256, 0, stream>>>(xb, Wqkv, bqkv, nullptr, Qs, Ks, Vts, 1024);
  attn_fwd<<<dim3(16, 64), 256, 0, stream>>>(Qs, Ks, Vts, AO);
  gemm_bt<1><<<dim3(8, 64), 256, 0, stream>>>(AO, Wo, bo, (float*)d_out,
                                              nullptr, nullptr, nullptr, 1024);
}

// Round 4
// 372.552 us; speedup vs baseline: 1.5062x; 1.5062x over previous
//
#include <hip/hip_runtime.h>

typedef __bf16 bf16x8 __attribute__((ext_vector_type(8)));
typedef float f32x4 __attribute__((ext_vector_type(4)));
typedef float f32x16 __attribute__((ext_vector_type(16)));
typedef unsigned short u16;
typedef unsigned int u32;

#define DEV static __device__ __forceinline__

DEV u16 f2bf(float f) {
  u32 u = __builtin_bit_cast(u32, f);
  u += 0x7fffu + ((u >> 16) & 1u);   // RNE (inputs are finite, no NaN handling)
  return (u16)(u >> 16);
}

DEV f32x4 mfma16(bf16x8 a, bf16x8 b, f32x4 c) {
  return __builtin_amdgcn_mfma_f32_16x16x32_bf16(a, b, c, 0, 0, 0);
}

DEV f32x16 mfma32(bf16x8 a, bf16x8 b, f32x16 c) {
  return __builtin_amdgcn_mfma_f32_32x32x16_bf16(a, b, c, 0, 0, 0);
}

DEV u32 cvtpk(float lo, float hi) {
  u32 r;
  asm("v_cvt_pk_bf16_f32 %0, %1, %2" : "=v"(r) : "v"(lo), "v"(hi));
  return r;
}

DEV void gload16(const void* g, void* l) {
  __builtin_amdgcn_global_load_lds((const __attribute__((address_space(1))) u32*)g,
                                   (__attribute__((address_space(3))) u32*)l, 16, 0, 0);
}

// ---------------- pack weights: Wqkv (3072x1024 bf16), Wo (1024x1024 bf16), bqkv ----------------
__global__ void pack_w(const float* __restrict__ wq, const float* __restrict__ wk,
                       const float* __restrict__ wv, const float* __restrict__ wo,
                       const float* __restrict__ bq, const float* __restrict__ bk,
                       const float* __restrict__ bv,
                       u16* __restrict__ Wqkv, u16* __restrict__ Wo, float* __restrict__ bqkv) {
  const int i = blockIdx.x * 256 + threadIdx.x;
  if (i < 3145728) {
    const int n = i >> 10;
    const float* s = (n < 1024) ? wq : (n < 2048) ? wk : wv;
    Wqkv[i] = f2bf(s[(n & 1023) * 1024 + (i & 1023)]);
  } else if (i < 4194304) {
    Wo[i - 3145728] = f2bf(wo[i - 3145728]);
  } else if (i < 4197376) {
    const int j = i - 4194304;
    bqkv[j] = (j < 1024) ? bq[j] : (j < 2048) ? bk[j - 1024] : bv[j - 2048];
  }
}

// ---------------- x -> bf16 ----------------
__global__ void cvt_x(const float4* __restrict__ x, u16* __restrict__ xb) {
  const int i = blockIdx.x * 256 + threadIdx.x;   // exactly 2,097,152 threads
  float4 v = x[i];
  union { u16 h[4]; uint2 d; } r;
  r.h[0] = f2bf(v.x); r.h[1] = f2bf(v.y); r.h[2] = f2bf(v.z); r.h[3] = f2bf(v.w);
  *(uint2*)&xb[(size_t)i * 4] = r.d;
}

// ---------------- GEMM C = A * B^T (+bias), A: MxK bf16 row-major, B: NxK bf16 row-major ----------
// MODE 0: QKV epilogue -> Q (scaled by log2e/8), K (B,H,T,Dh) and V^T (B,H,Dh,T), bf16
// MODE 1: plain fp32 C (M x 1024) + bias
template<int MODE>
__global__ __launch_bounds__(256)
void gemm_bt(const u16* __restrict__ A, const u16* __restrict__ B,
             const float* __restrict__ bias, float* __restrict__ Cf,
             u16* __restrict__ Qs, u16* __restrict__ Ks, u16* __restrict__ Vts,
             int K) {
  __shared__ u16 Asm[128 * 32];
  __shared__ u16 Bsm[128 * 32];
  const int tid = threadIdx.x, lane = tid & 63, w = tid >> 6;
  const int tn = blockIdx.x, tm = blockIdx.y;
  const int wr = w >> 1, wc = w & 1;
  f32x4 acc[4][4] = {};
  const size_t Kb = (size_t)K * 2;
  const char* Ab = (const char*)A + (size_t)(tm * 128) * Kb;
  const char* Bb = (const char*)B + (size_t)(tn * 128) * Kb;
  const int c0 = w * 2, c1 = c0 + 1;
  // chunk c covers LDS bytes [c*1024, c*1024+1024): row = c*16 + lane/4, colbyte = (lane%4)*16
  const size_t soff0 = (size_t)(c0 * 16 + (lane >> 2)) * Kb + (size_t)(lane & 3) * 16;
  const size_t soff1 = (size_t)(c1 * 16 + (lane >> 2)) * Kb + (size_t)(lane & 3) * 16;
  u16* la0 = Asm + c0 * 512;  u16* la1 = Asm + c1 * 512;
  u16* lb0 = Bsm + c0 * 512;  u16* lb1 = Bsm + c1 * 512;
  const int ar = (wr * 64 + (lane & 15)) * 32 + (lane >> 4) * 8;
  const int br = (wc * 64 + (lane & 15)) * 32 + (lane >> 4) * 8;

  for (int kt = 0; kt < K; kt += 32) {
    if (kt) __syncthreads();
    gload16(Ab + soff0 + (size_t)kt * 2, la0);
    gload16(Ab + soff1 + (size_t)kt * 2, la1);
    gload16(Bb + soff0 + (size_t)kt * 2, lb0);
    gload16(Bb + soff1 + (size_t)kt * 2, lb1);
    __syncthreads();
    bf16x8 af[4], bfv[4];
#pragma unroll
    for (int mf = 0; mf < 4; mf++) af[mf] = *(const bf16x8*)&Asm[ar + mf * 512];
#pragma unroll
    for (int nf = 0; nf < 4; nf++) bfv[nf] = *(const bf16x8*)&Bsm[br + nf * 512];
#pragma unroll
    for (int mf = 0; mf < 4; mf++)
#pragma unroll
      for (int nf = 0; nf < 4; nf++)
        acc[mf][nf] = mfma16(af[mf], bfv[nf], acc[mf][nf]);
  }

  // epilogue: C row m = ... + (lane>>4)*4 + r, col n = ... + (lane&15)
  const int nbase = tn * 128 + wc * 64 + (lane & 15);
  const int mbase = tm * 128 + wr * 64 + (lane >> 4) * 4;
  const float SCQ = 0.18033688011112042f;   // log2(e) / sqrt(64)
#pragma unroll
  for (int nf = 0; nf < 4; nf++) {
    const int n = nbase + nf * 16;
    const float bias_n = bias[n];
    if (MODE == 0) {
      const int sec = n >> 10;                 // 0=Q 1=K 2=V (tile cols never straddle)
      const int h = (n & 1023) >> 6, dh = n & 63;
#pragma unroll
      for (int mf = 0; mf < 4; mf++) {
#pragma unroll
        for (int r = 0; r < 4; r++) {
          const int m = mbase + mf * 16 + r;
          const int b = m >> 11, t = m & 2047;
          const size_t base = (size_t)(b * 16 + h) << 17;   // *131072
          const float vv = acc[mf][nf][r] + bias_n;
          if (sec == 0)      Qs[base + (size_t)t * 64 + dh] = f2bf(vv * SCQ);
          else if (sec == 1) Ks[base + (size_t)t * 64 + dh] = f2bf(vv);
          else               Vts[base + (size_t)dh * 2048 + t] = f2bf(vv);
        }
      }
    } else {
#pragma unroll
      for (int mf = 0; mf < 4; mf++)
#pragma unroll
        for (int r = 0; r < 4; r++) {
          const int m = mbase + mf * 16 + r;
          Cf[(size_t)m * 1024 + n] = acc[mf][nf][r] + bias_n;
        }
    }
  }
}

// ---------------- causal flash attention, swapped 32x32, LDS-free ----------------
// grid: (B*H, T/128). block 256 = 4 waves; wave w owns q rows [qt*128+w*32, +32).
// S^T = mfma32(K, Q^T): lane owns q = q0+(lane&31); k_local = (r&3)+8*(r>>2)+4*(lane>>5).
// No LDS, no barriers. K/V read direct from global (L2-resident per head).
__global__ __launch_bounds__(256)
void attn32(const u16* __restrict__ Qg, const u16* __restrict__ Kg,
            const u16* __restrict__ Vt, u16* __restrict__ AO) {
  const int lane = threadIdx.x & 63, w = threadIdx.x >> 6;
  const int bh = blockIdx.x, qt = blockIdx.y;
  const int l31 = lane & 31, h = lane >> 5;
  const int q0 = qt * 128 + w * 32;
  const size_t hb = (size_t)bh << 17;   // *131072 elements per (b,h)

  // Q^T B-frags (Q pre-scaled by log2e/8 in GEMM1): lane holds Q[q0+l31][s*16 + h*8 .. +8]
  bf16x8 qf[4];
  const u16* qrow_p = Qg + hb + (size_t)(q0 + l31) * 64 + h * 8;
#pragma unroll
  for (int s = 0; s < 4; s++) qf[s] = *(const bf16x8*)(qrow_p + s * 16);

  f32x16 o0 = {}, o1 = {};          // O^T accum: dh tiles 0-31 / 32-63, col q = l31
  float m = -3.0e38f, lr = 0.f;

  const u16* kp  = Kg + hb + (size_t)l31 * 64 + h * 8;
  const u16* vp0 = Vt + hb + (size_t)l31 * 2048 + h * 8;
  const u16* vp1 = Vt + hb + (size_t)(l31 + 32) * 2048 + h * 8;

  for (int kb = 0; kb <= q0; kb += 32) {
    const u16* kt = kp + (size_t)kb * 64;
    bf16x8 kf0 = *(const bf16x8*)(kt);
    bf16x8 kf1 = *(const bf16x8*)(kt + 16);
    bf16x8 kf2 = *(const bf16x8*)(kt + 32);
    bf16x8 kf3 = *(const bf16x8*)(kt + 48);
    f32x16 sa = {};
    sa = mfma32(kf0, qf[0], sa);
    sa = mfma32(kf1, qf[1], sa);
    sa = mfma32(kf2, qf[2], sa);
    sa = mfma32(kf3, qf[3], sa);

    if (kb == q0) {                  // only the diagonal tile needs masking
#pragma unroll
      for (int r = 0; r < 16; r++) {
        const int kl = (r & 3) + 8 * (r >> 2) + 4 * h;
        if (kl > l31) sa[r] = -3.0e38f;
      }
    }

    float pmax = sa[0];
#pragma unroll
    for (int r = 1; r < 16; r++) pmax = fmaxf(pmax, sa[r]);
    pmax = fmaxf(pmax, __shfl_xor(pmax, 32));

    if (!__all(pmax - m <= 8.0f)) {  // defer-max (T13): skip rescale when bounded
      const float mn = fmaxf(m, pmax);
      const float al = exp2f(m - mn);
      lr *= al;
#pragma unroll
      for (int r = 0; r < 16; r++) { o0[r] *= al; o1[r] *= al; }
      m = mn;
    }

    float e[16];
    float rs = 0.f;
#pragma unroll
    for (int r = 0; r < 16; r++) { e[r] = exp2f(sa[r] - m); rs += e[r]; }
    rs += __shfl_xor(rs, 32);
    lr += rs;

    // P -> bf16 B-frags: own pairs then half-swap via shfl_xor(32) + select
    u32 W[8];
#pragma unroll
    for (int j = 0; j < 8; j++) W[j] = cvtpk(e[2 * j], e[2 * j + 1]);
    union { u32 u[4]; bf16x8 v; } f0, f1;
    {
      const u32 x0 = __shfl_xor(W[0], 32), x1 = __shfl_xor(W[1], 32);
      const u32 x2 = __shfl_xor(W[2], 32), x3 = __shfl_xor(W[3], 32);
      f0.u[0] = h ? x2 : W[0]; f0.u[1] = h ? x3 : W[1];
      f0.u[2] = h ? W[2] : x0; f0.u[3] = h ? W[3] : x1;
      const u32 y0 = __shfl_xor(W[4], 32), y1 = __shfl_xor(W[5], 32);
      const u32 y2 = __shfl_xor(W[6], 32), y3 = __shfl_xor(W[7], 32);
      f1.u[0] = h ? y2 : W[4]; f1.u[1] = h ? y3 : W[5];
      f1.u[2] = h ? W[6] : y0; f1.u[3] = h ? W[7] : y1;
    }

    // PV: O^T += V^T-slice (A) * P^T-slice (B)
    bf16x8 v00 = *(const bf16x8*)(vp0 + kb);
    bf16x8 v01 = *(const bf16x8*)(vp0 + kb + 16);
    bf16x8 v10 = *(const bf16x8*)(vp1 + kb);
    bf16x8 v11 = *(const bf16x8*)(vp1 + kb + 16);
    o0 = mfma32(v00, f0.v, o0);
    o0 = mfma32(v01, f1.v, o0);
    o1 = mfma32(v10, f0.v, o1);
    o1 = mfma32(v11, f1.v, o1);
  }

  const float inv = 1.0f / lr;
  const int b = bh >> 4, hh = bh & 15;
  const int q = q0 + l31;
  u16* orow = AO + (size_t)(b * 2048 + q) * 1024 + hh * 64;
#pragma unroll
  for (int r = 0; r < 16; r += 2) {
    const int dh = (r & 3) + 8 * (r >> 2) + 4 * h;   // r even -> pairs (dh, dh+1)
    *(u32*)(orow + dh)      = cvtpk(o0[r] * inv, o0[r + 1] * inv);
    *(u32*)(orow + 32 + dh) = cvtpk(o1[r] * inv, o1[r + 1] * inv);
  }
}

extern "C" void kernel_launch(void* const* d_in, const int* in_sizes, int n_in,
                              void* d_out, int out_size, void* d_ws, size_t ws_size,
                              hipStream_t stream) {
  const float* x  = (const float*)d_in[0];
  const float* wq = (const float*)d_in[1];
  const float* bq = (const float*)d_in[2];
  const float* wk = (const float*)d_in[3];
  const float* bk = (const float*)d_in[4];
  const float* wv = (const float*)d_in[5];
  const float* bv = (const float*)d_in[6];
  const float* wo = (const float*)d_in[7];
  const float* bo = (const float*)d_in[8];

  char* p = (char*)d_ws;
  u16* xb    = (u16*)p;   p += 16777216;   // 8192x1024 bf16; reused as AO after GEMM1
  u16* Wqkv  = (u16*)p;   p += 6291456;    // 3072x1024 bf16
  u16* Wo    = (u16*)p;   p += 2097152;    // 1024x1024 bf16
  float* bqkv = (float*)p; p += 12288;     // 3072 fp32
  u16* Qs    = (u16*)p;   p += 16777216;   // (B,H,T,Dh) bf16, pre-scaled by log2e/8
  u16* Ks    = (u16*)p;   p += 16777216;   // (B,H,T,Dh) bf16
  u16* Vts   = (u16*)p;   p += 16777216;   // (B,H,Dh,T) bf16
  u16* AO    = xb;                         // attention output (B,T,H*Dh) bf16 — aliases xb

  pack_w<<<16396, 256, 0, stream>>>(wq, wk, wv, wo, bq, bk, bv, Wqkv, Wo, bqkv);
  cvt_x<<<8192, 256, 0, stream>>>((const float4*)x, xb);
  gemm_bt<0><<<dim3(24, 64), 256, 0, stream>>>(xb, Wqkv, bqkv, nullptr, Qs, Ks, Vts, 1024);
  attn32<<<dim3(64, 16), 256, 0, stream>>>(Qs, Ks, Vts, AO);
  gemm_bt<1><<<dim3(8, 64), 256, 0, stream>>>(AO, Wo, bo, (float*)d_out,
                                              nullptr, nullptr, nullptr, 1024);
}

// Round 6
// 367.021 us; speedup vs baseline: 1.5289x; 1.0151x over previous
//
#include <hip/hip_runtime.h>

typedef __bf16 bf16x8 __attribute__((ext_vector_type(8)));
typedef float f32x4 __attribute__((ext_vector_type(4)));
typedef float f32x16 __attribute__((ext_vector_type(16)));
typedef unsigned short u16;
typedef unsigned int u32;

#define DEV static __device__ __forceinline__

DEV u16 f2bf(float f) {
  u32 u = __builtin_bit_cast(u32, f);
  u += 0x7fffu + ((u >> 16) & 1u);   // RNE (inputs are finite, no NaN handling)
  return (u16)(u >> 16);
}

DEV f32x4 mfma16(bf16x8 a, bf16x8 b, f32x4 c) {
  return __builtin_amdgcn_mfma_f32_16x16x32_bf16(a, b, c, 0, 0, 0);
}

DEV f32x16 mfma32(bf16x8 a, bf16x8 b, f32x16 c) {
  return __builtin_amdgcn_mfma_f32_32x32x16_bf16(a, b, c, 0, 0, 0);
}

DEV u32 cvtpk(float lo, float hi) {
  u32 r;
  asm("v_cvt_pk_bf16_f32 %0, %1, %2" : "=v"(r) : "v"(lo), "v"(hi));
  return r;
}

DEV void gload16(const void* g, void* l) {
  __builtin_amdgcn_global_load_lds((const __attribute__((address_space(1))) u32*)g,
                                   (__attribute__((address_space(3))) u32*)l, 16, 0, 0);
}

// ---------------- pack weights: Wqkv (3072x1024 bf16), Wo (1024x1024 bf16), bqkv ----------------
__global__ void pack_w(const float* __restrict__ wq, const float* __restrict__ wk,
                       const float* __restrict__ wv, const float* __restrict__ wo,
                       const float* __restrict__ bq, const float* __restrict__ bk,
                       const float* __restrict__ bv,
                       u16* __restrict__ Wqkv, u16* __restrict__ Wo, float* __restrict__ bqkv) {
  const int i = blockIdx.x * 256 + threadIdx.x;
  if (i < 3145728) {
    const int n = i >> 10;
    const float* s = (n < 1024) ? wq : (n < 2048) ? wk : wv;
    Wqkv[i] = f2bf(s[(n & 1023) * 1024 + (i & 1023)]);
  } else if (i < 4194304) {
    Wo[i - 3145728] = f2bf(wo[i - 3145728]);
  } else if (i < 4197376) {
    const int j = i - 4194304;
    bqkv[j] = (j < 1024) ? bq[j] : (j < 2048) ? bk[j - 1024] : bv[j - 2048];
  }
}

// ---------------- x -> bf16 ----------------
__global__ void cvt_x(const float4* __restrict__ x, u16* __restrict__ xb) {
  const int i = blockIdx.x * 256 + threadIdx.x;   // exactly 2,097,152 threads
  float4 v = x[i];
  union { u16 h[4]; uint2 d; } r;
  r.h[0] = f2bf(v.x); r.h[1] = f2bf(v.y); r.h[2] = f2bf(v.z); r.h[3] = f2bf(v.w);
  *(uint2*)&xb[(size_t)i * 4] = r.d;
}

// ---------------- GEMM C = A * B^T (+bias), A: MxK bf16 row-major, B: NxK bf16 row-major ----------
// MODE 0: QKV epilogue -> Q (scaled by log2e/8), K (B,H,T,Dh) and V^T (B,H,Dh,T), bf16
// MODE 1: plain fp32 C (M x 1024) + bias
template<int MODE>
__global__ __launch_bounds__(256)
void gemm_bt(const u16* __restrict__ A, const u16* __restrict__ B,
             const float* __restrict__ bias, float* __restrict__ Cf,
             u16* __restrict__ Qs, u16* __restrict__ Ks, u16* __restrict__ Vts,
             int K) {
  __shared__ u16 Asm[128 * 32];
  __shared__ u16 Bsm[128 * 32];
  const int tid = threadIdx.x, lane = tid & 63, w = tid >> 6;
  const int tn = blockIdx.x, tm = blockIdx.y;
  const int wr = w >> 1, wc = w & 1;
  f32x4 acc[4][4] = {};
  const size_t Kb = (size_t)K * 2;
  const char* Ab = (const char*)A + (size_t)(tm * 128) * Kb;
  const char* Bb = (const char*)B + (size_t)(tn * 128) * Kb;
  const int c0 = w * 2, c1 = c0 + 1;
  // chunk c covers LDS bytes [c*1024, c*1024+1024): row = c*16 + lane/4, colbyte = (lane%4)*16
  const size_t soff0 = (size_t)(c0 * 16 + (lane >> 2)) * Kb + (size_t)(lane & 3) * 16;
  const size_t soff1 = (size_t)(c1 * 16 + (lane >> 2)) * Kb + (size_t)(lane & 3) * 16;
  u16* la0 = Asm + c0 * 512;  u16* la1 = Asm + c1 * 512;
  u16* lb0 = Bsm + c0 * 512;  u16* lb1 = Bsm + c1 * 512;
  const int ar = (wr * 64 + (lane & 15)) * 32 + (lane >> 4) * 8;
  const int br = (wc * 64 + (lane & 15)) * 32 + (lane >> 4) * 8;

  for (int kt = 0; kt < K; kt += 32) {
    if (kt) __syncthreads();
    gload16(Ab + soff0 + (size_t)kt * 2, la0);
    gload16(Ab + soff1 + (size_t)kt * 2, la1);
    gload16(Bb + soff0 + (size_t)kt * 2, lb0);
    gload16(Bb + soff1 + (size_t)kt * 2, lb1);
    __syncthreads();
    bf16x8 af[4], bfv[4];
#pragma unroll
    for (int mf = 0; mf < 4; mf++) af[mf] = *(const bf16x8*)&Asm[ar + mf * 512];
#pragma unroll
    for (int nf = 0; nf < 4; nf++) bfv[nf] = *(const bf16x8*)&Bsm[br + nf * 512];
#pragma unroll
    for (int mf = 0; mf < 4; mf++)
#pragma unroll
      for (int nf = 0; nf < 4; nf++)
        acc[mf][nf] = mfma16(af[mf], bfv[nf], acc[mf][nf]);
  }

  // epilogue: C row m = ... + (lane>>4)*4 + r, col n = ... + (lane&15)
  const int nbase = tn * 128 + wc * 64 + (lane & 15);
  const int mbase = tm * 128 + wr * 64 + (lane >> 4) * 4;
  const float SCQ = 0.18033688011112042f;   // log2(e) / sqrt(64)
#pragma unroll
  for (int nf = 0; nf < 4; nf++) {
    const int n = nbase + nf * 16;
    const float bias_n = bias[n];
    if (MODE == 0) {
      const int sec = n >> 10;                 // 0=Q 1=K 2=V (tile cols never straddle)
      const int h = (n & 1023) >> 6, dh = n & 63;
#pragma unroll
      for (int mf = 0; mf < 4; mf++) {
#pragma unroll
        for (int r = 0; r < 4; r++) {
          const int m = mbase + mf * 16 + r;
          const int b = m >> 11, t = m & 2047;
          const size_t base = (size_t)(b * 16 + h) << 17;   // *131072
          const float vv = acc[mf][nf][r] + bias_n;
          if (sec == 0)      Qs[base + (size_t)t * 64 + dh] = f2bf(vv * SCQ);
          else if (sec == 1) Ks[base + (size_t)t * 64 + dh] = f2bf(vv);
          else               Vts[base + (size_t)dh * 2048 + t] = f2bf(vv);
        }
      }
    } else {
#pragma unroll
      for (int mf = 0; mf < 4; mf++)
#pragma unroll
        for (int r = 0; r < 4; r++) {
          const int m = mbase + mf * 16 + r;
          Cf[(size_t)m * 1024 + n] = acc[mf][nf][r] + bias_n;
        }
    }
  }
}

// ---------------- causal flash attention, swapped 32x32, LDS-free, pipelined ----------------
// grid: (B*H, 16 perm'd q-tiles). block 256 = 4 waves; wave w owns q rows [qt*128+w*32, +32).
// Balanced qt permutation: each CU's 4 resident blocks get qt summing to exactly 30.
// Per tile: V loads issued at top (hide under QK+softmax); K double-buffered (prefetch t+1
// after QK mfmas); P half-swap via v_permlane32_swap_b32; setprio around MFMA clusters.
__global__ __launch_bounds__(256, 4)
void attn32(const u16* __restrict__ Qg, const u16* __restrict__ Kg,
            const u16* __restrict__ Vt, u16* __restrict__ AO) {
  const int lane = threadIdx.x & 63, w = threadIdx.x >> 6;
  const int bh = blockIdx.x;
  const int yy = blockIdx.y;
  const int gq = yy >> 2, oq = yy & 3;
  const int qt = (gq == 0) ? oq : (gq == 1) ? 15 - oq : (gq == 2) ? 4 + oq : 11 - oq;
  const int l31 = lane & 31, h = lane >> 5;
  const int q0 = qt * 128 + w * 32;
  const size_t hb = (size_t)bh << 17;   // *131072 elements per (b,h)

  // Q^T B-frags (Q pre-scaled by log2e/8 in GEMM1): lane holds Q[q0+l31][s*16 + h*8 .. +8]
  bf16x8 qf[4];
  const u16* qrow_p = Qg + hb + (size_t)(q0 + l31) * 64 + h * 8;
#pragma unroll
  for (int s = 0; s < 4; s++) qf[s] = *(const bf16x8*)(qrow_p + s * 16);

  f32x16 o0 = {}, o1 = {};          // O^T accum: dh tiles 0-31 / 32-63, col q = l31
  float m = -3.0e38f, lr = 0.f;

  const u16* kp  = Kg + hb + (size_t)l31 * 64 + h * 8;
  const u16* vp0 = Vt + hb + (size_t)l31 * 2048 + h * 8;
  const u16* vp1 = vp0 + 32 * 2048;

  bf16x8 kA[4], kB[4];
#pragma unroll
  for (int j = 0; j < 4; j++) kA[j] = *(const bf16x8*)(kp + j * 16);

  auto step = [&](bf16x8 (&kc)[4], bf16x8 (&kn)[4], int kb) {
    // V loads for THIS tile — issued first, land under QK + softmax
    bf16x8 vc0 = *(const bf16x8*)(vp0 + kb);
    bf16x8 vc1 = *(const bf16x8*)(vp0 + kb + 16);
    bf16x8 vc2 = *(const bf16x8*)(vp1 + kb);
    bf16x8 vc3 = *(const bf16x8*)(vp1 + kb + 16);

    f32x16 sa = {};
    __builtin_amdgcn_s_setprio(1);
    sa = mfma32(kc[0], qf[0], sa);
    sa = mfma32(kc[1], qf[1], sa);
    sa = mfma32(kc[2], qf[2], sa);
    sa = mfma32(kc[3], qf[3], sa);
    __builtin_amdgcn_s_setprio(0);

    // K prefetch for NEXT tile — in flight across softmax + PV
    if (kb + 32 <= q0) {
      const u16* kt2 = kp + (size_t)(kb + 32) * 64;
#pragma unroll
      for (int j = 0; j < 4; j++) kn[j] = *(const bf16x8*)(kt2 + j * 16);
    }

    if (kb == q0) {                  // only the diagonal tile needs masking
#pragma unroll
      for (int r = 0; r < 16; r++) {
        const int kl = (r & 3) + 8 * (r >> 2) + 4 * h;
        if (kl > l31) sa[r] = -3.0e38f;
      }
    }

    float pmax = fmaxf(sa[0], sa[1]);
#pragma unroll
    for (int r = 2; r < 16; r++) pmax = fmaxf(pmax, sa[r]);
    pmax = fmaxf(pmax, __shfl_xor(pmax, 32));

    if (!__all(pmax - m <= 8.0f)) {  // defer-max (T13): skip rescale when bounded
      const float mn = fmaxf(m, pmax);
      const float al = exp2f(m - mn);
      lr *= al;
#pragma unroll
      for (int r = 0; r < 16; r++) { o0[r] *= al; o1[r] *= al; }
      m = mn;
    }

    // fused exp2 / row-sum / bf16-pack (no e[] array -> lower VGPR)
    u32 W[8];
    float rs = 0.f;
#pragma unroll
    for (int j = 0; j < 8; j++) {
      const float e0 = exp2f(sa[2 * j] - m);
      const float e1 = exp2f(sa[2 * j + 1] - m);
      rs += e0 + e1;
      W[j] = cvtpk(e0, e1);
    }
    rs += __shfl_xor(rs, 32);
    lr += rs;

    // half-swap: W0<->W2, W1<->W3, W4<->W6, W5<->W7 (hi/lo 32-lane exchange)
    asm volatile("v_permlane32_swap_b32 %0, %1" : "+v"(W[0]), "+v"(W[2]));
    asm volatile("v_permlane32_swap_b32 %0, %1" : "+v"(W[1]), "+v"(W[3]));
    asm volatile("v_permlane32_swap_b32 %0, %1" : "+v"(W[4]), "+v"(W[6]));
    asm volatile("v_permlane32_swap_b32 %0, %1" : "+v"(W[5]), "+v"(W[7]));
    union { u32 u[4]; bf16x8 v; } f0, f1;
    f0.u[0] = W[0]; f0.u[1] = W[1]; f0.u[2] = W[2]; f0.u[3] = W[3];
    f1.u[0] = W[4]; f1.u[1] = W[5]; f1.u[2] = W[6]; f1.u[3] = W[7];

    __builtin_amdgcn_s_setprio(1);
    o0 = mfma32(vc0, f0.v, o0);
    o0 = mfma32(vc1, f1.v, o0);
    o1 = mfma32(vc2, f0.v, o1);
    o1 = mfma32(vc3, f1.v, o1);
    __builtin_amdgcn_s_setprio(0);
  };

  int kb = 0;
  for (;;) {
    step(kA, kB, kb);
    kb += 32; if (kb > q0) break;
    step(kB, kA, kb);
    kb += 32; if (kb > q0) break;
  }

  const float inv = 1.0f / lr;
  const int b = bh >> 4, hh = bh & 15;
  const int q = q0 + l31;
  u16* orow = AO + (size_t)(b * 2048 + q) * 1024 + hh * 64;
#pragma unroll
  for (int r = 0; r < 16; r += 2) {
    const int dh = (r & 3) + 8 * (r >> 2) + 4 * h;   // r even -> pairs (dh, dh+1)
    *(u32*)(orow + dh)      = cvtpk(o0[r] * inv, o0[r + 1] * inv);
    *(u32*)(orow + 32 + dh) = cvtpk(o1[r] * inv, o1[r + 1] * inv);
  }
}

extern "C" void kernel_launch(void* const* d_in, const int* in_sizes, int n_in,
                              void* d_out, int out_size, void* d_ws, size_t ws_size,
                              hipStream_t stream) {
  const float* x  = (const float*)d_in[0];
  const float* wq = (const float*)d_in[1];
  const float* bq = (const float*)d_in[2];
  const float* wk = (const float*)d_in[3];
  const float* bk = (const float*)d_in[4];
  const float* wv = (const float*)d_in[5];
  const float* bv = (const float*)d_in[6];
  const float* wo = (const float*)d_in[7];
  const float* bo = (const float*)d_in[8];

  char* p = (char*)d_ws;
  u16* xb    = (u16*)p;   p += 16777216;   // 8192x1024 bf16; reused as AO after GEMM1
  u16* Wqkv  = (u16*)p;   p += 6291456;    // 3072x1024 bf16
  u16* Wo    = (u16*)p;   p += 2097152;    // 1024x1024 bf16
  float* bqkv = (float*)p; p += 12288;     // 3072 fp32
  u16* Qs    = (u16*)p;   p += 16777216;   // (B,H,T,Dh) bf16, pre-scaled by log2e/8
  u16* Ks    = (u16*)p;   p += 16777216;   // (B,H,T,Dh) bf16
  u16* Vts   = (u16*)p;   p += 16777216;   // (B,H,Dh,T) bf16
  u16* AO    = xb;                         // attention output (B,T,H*Dh) bf16 — aliases xb

  pack_w<<<16396, 256, 0, stream>>>(wq, wk, wv, wo, bq, bk, bv, Wqkv, Wo, bqkv);
  cvt_x<<<8192, 256, 0, stream>>>((const float4*)x, xb);
  gemm_bt<0><<<dim3(24, 64), 256, 0, stream>>>(xb, Wqkv, bqkv, nullptr, Qs, Ks, Vts, 1024);
  attn32<<<dim3(64, 16), 256, 0, stream>>>(Qs, Ks, Vts, AO);
  gemm_bt<1><<<dim3(8, 64), 256, 0, stream>>>(AO, Wo, bo, (float*)d_out,
                                              nullptr, nullptr, nullptr, 1024);
}

// Round 9
// 353.919 us; speedup vs baseline: 1.5855x; 1.0370x over previous
//
#include <hip/hip_runtime.h>

typedef __bf16 bf16x8 __attribute__((ext_vector_type(8)));
typedef float f32x4 __attribute__((ext_vector_type(4)));
typedef float f32x16 __attribute__((ext_vector_type(16)));
typedef unsigned short u16;
typedef unsigned int u32;
typedef unsigned int u32x2 __attribute__((ext_vector_type(2)));

#define DEV static __device__ __forceinline__

#if __has_builtin(__builtin_amdgcn_permlane32_swap)
#define PLSWAP_BUILTIN 1
#endif

DEV u32 f2u(float f) { return __builtin_bit_cast(u32, f); }
DEV float u2f(u32 u) { return __builtin_bit_cast(float, u); }

DEV u16 f2bf(float f) {
  u32 u = __builtin_bit_cast(u32, f);
  u += 0x7fffu + ((u >> 16) & 1u);   // RNE (inputs are finite, no NaN handling)
  return (u16)(u >> 16);
}

DEV f32x4 mfma16(bf16x8 a, bf16x8 b, f32x4 c) {
  return __builtin_amdgcn_mfma_f32_16x16x32_bf16(a, b, c, 0, 0, 0);
}

DEV f32x16 mfma32(bf16x8 a, bf16x8 b, f32x16 c) {
  return __builtin_amdgcn_mfma_f32_32x32x16_bf16(a, b, c, 0, 0, 0);
}

DEV u32 cvtpk(float lo, float hi) {
  u32 r;
  asm("v_cvt_pk_bf16_f32 %0, %1, %2" : "=v"(r) : "v"(lo), "v"(hi));
  return r;
}

// Cross-half (lane ^ 32) reduction. PITFALL (R7/R8 NaN): V_PERMLANE32_SWAP
// must not read a VGPR written by the immediately preceding VALU instr
// (wait-state hazard); hand-rolled mov+swap inside one asm block violates it.
// Use the BUILTIN so the compiler inserts hazard nops. Semantics (verified on
// HW by R6's passing P-swap): {na, nb} = plswap(a, b) -> na = [a.lo|b.lo],
// nb = [a.hi|b.hi]. With a = b = x: na/nb broadcast the two halves -> one
// fmax/add gives every lane red(x[l], x[l^32]).
DEV float hred_max(float x) {
#ifdef PLSWAP_BUILTIN
  u32x2 r = __builtin_amdgcn_permlane32_swap(f2u(x), f2u(x), false, false);
  return fmaxf(u2f(r.x), u2f(r.y));
#else
  return fmaxf(x, __shfl_xor(x, 32));
#endif
}
DEV float hred_add(float x) {
#ifdef PLSWAP_BUILTIN
  u32x2 r = __builtin_amdgcn_permlane32_swap(f2u(x), f2u(x), false, false);
  return u2f(r.x) + u2f(r.y);
#else
  return x + __shfl_xor(x, 32);
#endif
}

DEV void gload16(const void* g, void* l) {
  __builtin_amdgcn_global_load_lds((const __attribute__((address_space(1))) u32*)g,
                                   (__attribute__((address_space(3))) u32*)l, 16, 0, 0);
}

// ---------------- pack weights: Wqkv (3072x1024 bf16), Wo (1024x1024 bf16), bqkv ----------------
__global__ void pack_w(const float* __restrict__ wq, const float* __restrict__ wk,
                       const float* __restrict__ wv, const float* __restrict__ wo,
                       const float* __restrict__ bq, const float* __restrict__ bk,
                       const float* __restrict__ bv,
                       u16* __restrict__ Wqkv, u16* __restrict__ Wo, float* __restrict__ bqkv) {
  const int i = blockIdx.x * 256 + threadIdx.x;
  if (i < 3145728) {
    const int n = i >> 10;
    const float* s = (n < 1024) ? wq : (n < 2048) ? wk : wv;
    Wqkv[i] = f2bf(s[(n & 1023) * 1024 + (i & 1023)]);
  } else if (i < 4194304) {
    Wo[i - 3145728] = f2bf(wo[i - 3145728]);
  } else if (i < 4197376) {
    const int j = i - 4194304;
    bqkv[j] = (j < 1024) ? bq[j] : (j < 2048) ? bk[j - 1024] : bv[j - 2048];
  }
}

// ---------------- x -> bf16 ----------------
__global__ void cvt_x(const float4* __restrict__ x, u16* __restrict__ xb) {
  const int i = blockIdx.x * 256 + threadIdx.x;   // exactly 2,097,152 threads
  float4 v = x[i];
  union { u16 h[4]; uint2 d; } r;
  r.h[0] = f2bf(v.x); r.h[1] = f2bf(v.y); r.h[2] = f2bf(v.z); r.h[3] = f2bf(v.w);
  *(uint2*)&xb[(size_t)i * 4] = r.d;
}

// ---------------- GEMM C = A * B^T (+bias), A: MxK bf16 row-major, B: NxK bf16 row-major ----------
// MODE 0: QKV epilogue -> Q (scaled by log2e/8), K (B,H,T,Dh) and V^T (B,H,Dh,T), bf16
// MODE 1: plain fp32 C (M x 1024) + bias
template<int MODE>
__global__ __launch_bounds__(256)
void gemm_bt(const u16* __restrict__ A, const u16* __restrict__ B,
             const float* __restrict__ bias, float* __restrict__ Cf,
             u16* __restrict__ Qs, u16* __restrict__ Ks, u16* __restrict__ Vts,
             int K) {
  __shared__ u16 Asm[128 * 32];
  __shared__ u16 Bsm[128 * 32];
  const int tid = threadIdx.x, lane = tid & 63, w = tid >> 6;
  const int tn = blockIdx.x, tm = blockIdx.y;
  const int wr = w >> 1, wc = w & 1;
  f32x4 acc[4][4] = {};
  const size_t Kb = (size_t)K * 2;
  const char* Ab = (const char*)A + (size_t)(tm * 128) * Kb;
  const char* Bb = (const char*)B + (size_t)(tn * 128) * Kb;
  const int c0 = w * 2, c1 = c0 + 1;
  // chunk c covers LDS bytes [c*1024, c*1024+1024): row = c*16 + lane/4, colbyte = (lane%4)*16
  const size_t soff0 = (size_t)(c0 * 16 + (lane >> 2)) * Kb + (size_t)(lane & 3) * 16;
  const size_t soff1 = (size_t)(c1 * 16 + (lane >> 2)) * Kb + (size_t)(lane & 3) * 16;
  u16* la0 = Asm + c0 * 512;  u16* la1 = Asm + c1 * 512;
  u16* lb0 = Bsm + c0 * 512;  u16* lb1 = Bsm + c1 * 512;
  const int ar = (wr * 64 + (lane & 15)) * 32 + (lane >> 4) * 8;
  const int br = (wc * 64 + (lane & 15)) * 32 + (lane >> 4) * 8;

  for (int kt = 0; kt < K; kt += 32) {
    if (kt) __syncthreads();
    gload16(Ab + soff0 + (size_t)kt * 2, la0);
    gload16(Ab + soff1 + (size_t)kt * 2, la1);
    gload16(Bb + soff0 + (size_t)kt * 2, lb0);
    gload16(Bb + soff1 + (size_t)kt * 2, lb1);
    __syncthreads();
    bf16x8 af[4], bfv[4];
#pragma unroll
    for (int mf = 0; mf < 4; mf++) af[mf] = *(const bf16x8*)&Asm[ar + mf * 512];
#pragma unroll
    for (int nf = 0; nf < 4; nf++) bfv[nf] = *(const bf16x8*)&Bsm[br + nf * 512];
#pragma unroll
    for (int mf = 0; mf < 4; mf++)
#pragma unroll
      for (int nf = 0; nf < 4; nf++)
        acc[mf][nf] = mfma16(af[mf], bfv[nf], acc[mf][nf]);
  }

  // epilogue: C row m = ... + (lane>>4)*4 + r, col n = ... + (lane&15)
  const int nbase = tn * 128 + wc * 64 + (lane & 15);
  const int mbase = tm * 128 + wr * 64 + (lane >> 4) * 4;
  const float SCQ = 0.18033688011112042f;   // log2(e) / sqrt(64)
#pragma unroll
  for (int nf = 0; nf < 4; nf++) {
    const int n = nbase + nf * 16;
    const float bias_n = bias[n];
    if (MODE == 0) {
      const int sec = n >> 10;                 // 0=Q 1=K 2=V (tile cols never straddle)
      const int h = (n & 1023) >> 6, dh = n & 63;
#pragma unroll
      for (int mf = 0; mf < 4; mf++) {
#pragma unroll
        for (int r = 0; r < 4; r++) {
          const int m = mbase + mf * 16 + r;
          const int b = m >> 11, t = m & 2047;
          const size_t base = (size_t)(b * 16 + h) << 17;   // *131072
          const float vv = acc[mf][nf][r] + bias_n;
          if (sec == 0)      Qs[base + (size_t)t * 64 + dh] = f2bf(vv * SCQ);
          else if (sec == 1) Ks[base + (size_t)t * 64 + dh] = f2bf(vv);
          else               Vts[base + (size_t)dh * 2048 + t] = f2bf(vv);
        }
      }
    } else {
#pragma unroll
      for (int mf = 0; mf < 4; mf++)
#pragma unroll
        for (int r = 0; r < 4; r++) {
          const int m = mbase + mf * 16 + r;
          Cf[(size_t)m * 1024 + n] = acc[mf][nf][r] + bias_n;
        }
    }
  }
}

// ---------------- causal flash attention, swapped 32x32, LDS-free, 1-wave blocks ----------------
// grid: (B*H, 64 q-tiles of 32 rows, longest-first). block = 64 threads = 1 wave.
// 4096 blocks -> hardware backfill smooths the causal tail; no barriers at all.
// S^T = mfma32(K, Q^T): lane owns q = q0+(lane&31); k_local = (r&3)+8*(r>>2)+4*(lane>>5).
// Cross-half reductions + P half-swap via permlane32_swap builtin (VALU, no LDS path).
__global__ __launch_bounds__(64, 4)
void attn32(const u16* __restrict__ Qg, const u16* __restrict__ Kg,
            const u16* __restrict__ Vt, u16* __restrict__ AO) {
  const int lane = threadIdx.x;
  const int bh = blockIdx.x;
  const int qi = 63 - (int)blockIdx.y;     // longest tiles dispatch first
  const int l31 = lane & 31, h = lane >> 5;
  const int q0 = qi * 32;
  const size_t hb = (size_t)bh << 17;   // *131072 elements per (b,h)

  // Q^T B-frags (Q pre-scaled by log2e/8 in GEMM1): lane holds Q[q0+l31][s*16 + h*8 .. +8]
  bf16x8 qf[4];
  const u16* qrow_p = Qg + hb + (size_t)(q0 + l31) * 64 + h * 8;
#pragma unroll
  for (int s = 0; s < 4; s++) qf[s] = *(const bf16x8*)(qrow_p + s * 16);

  f32x16 o0 = {}, o1 = {};          // O^T accum: dh tiles 0-31 / 32-63, col q = l31
  float m = -3.0e38f, lr = 0.f;

  const u16* kp  = Kg + hb + (size_t)l31 * 64 + h * 8;
  const u16* vp0 = Vt + hb + (size_t)l31 * 2048 + h * 8;
  const u16* vp1 = vp0 + 32 * 2048;

  bf16x8 kA[4], kB[4];
#pragma unroll
  for (int j = 0; j < 4; j++) kA[j] = *(const bf16x8*)(kp + j * 16);

  auto step = [&](bf16x8 (&kc)[4], bf16x8 (&kn)[4], int kb) {
    // V loads for THIS tile — issued first, land under QK + softmax
    bf16x8 vc0 = *(const bf16x8*)(vp0 + kb);
    bf16x8 vc1 = *(const bf16x8*)(vp0 + kb + 16);
    bf16x8 vc2 = *(const bf16x8*)(vp1 + kb);
    bf16x8 vc3 = *(const bf16x8*)(vp1 + kb + 16);

    f32x16 sa = {};
    __builtin_amdgcn_s_setprio(1);
    sa = mfma32(kc[0], qf[0], sa);
    sa = mfma32(kc[1], qf[1], sa);
    sa = mfma32(kc[2], qf[2], sa);
    sa = mfma32(kc[3], qf[3], sa);
    __builtin_amdgcn_s_setprio(0);

    // K prefetch for NEXT tile — in flight across softmax + PV
    if (kb + 32 <= q0) {
      const u16* kt2 = kp + (size_t)(kb + 32) * 64;
#pragma unroll
      for (int j = 0; j < 4; j++) kn[j] = *(const bf16x8*)(kt2 + j * 16);
    }

    if (kb == q0) {                  // only the diagonal tile needs masking
#pragma unroll
      for (int r = 0; r < 16; r++) {
        const int kl = (r & 3) + 8 * (r >> 2) + 4 * h;
        if (kl > l31) sa[r] = -3.0e38f;
      }
    }

    float pmax = fmaxf(sa[0], sa[1]);
#pragma unroll
    for (int r = 2; r < 16; r++) pmax = fmaxf(pmax, sa[r]);
    pmax = hred_max(pmax);           // cross-half reduce

    if (!__all(pmax - m <= 8.0f)) {  // defer-max (T13): skip rescale when bounded
      const float mn = fmaxf(m, pmax);
      const float al = exp2f(m - mn);
      lr *= al;
#pragma unroll
      for (int r = 0; r < 16; r++) { o0[r] *= al; o1[r] *= al; }
      m = mn;
    }

    // fused exp2 / row-sum / bf16-pack (no e[] array -> lower VGPR)
    u32 W[8];
    float rs = 0.f;
#pragma unroll
    for (int j = 0; j < 8; j++) {
      const float e0 = exp2f(sa[2 * j] - m);
      const float e1 = exp2f(sa[2 * j + 1] - m);
      rs += e0 + e1;
      W[j] = cvtpk(e0, e1);
    }
    lr += hred_add(rs);              // cross-half reduce

    // half-swap: W0<->W2, W1<->W3, W4<->W6, W5<->W7 (hi/lo 32-lane exchange)
    union { u32 u[4]; bf16x8 v; } f0, f1;
#ifdef PLSWAP_BUILTIN
    {
      u32x2 r02 = __builtin_amdgcn_permlane32_swap(W[0], W[2], false, false);
      u32x2 r13 = __builtin_amdgcn_permlane32_swap(W[1], W[3], false, false);
      u32x2 r46 = __builtin_amdgcn_permlane32_swap(W[4], W[6], false, false);
      u32x2 r57 = __builtin_amdgcn_permlane32_swap(W[5], W[7], false, false);
      f0.u[0] = r02.x; f0.u[1] = r13.x; f0.u[2] = r02.y; f0.u[3] = r13.y;
      f1.u[0] = r46.x; f1.u[1] = r57.x; f1.u[2] = r46.y; f1.u[3] = r57.y;
    }
#else
    // R6-HW-proven asm path (sources written by separate earlier asm blocks)
    asm volatile("v_permlane32_swap_b32 %0, %1" : "+v"(W[0]), "+v"(W[2]));
    asm volatile("v_permlane32_swap_b32 %0, %1" : "+v"(W[1]), "+v"(W[3]));
    asm volatile("v_permlane32_swap_b32 %0, %1" : "+v"(W[4]), "+v"(W[6]));
    asm volatile("v_permlane32_swap_b32 %0, %1" : "+v"(W[5]), "+v"(W[7]));
    f0.u[0] = W[0]; f0.u[1] = W[1]; f0.u[2] = W[2]; f0.u[3] = W[3];
    f1.u[0] = W[4]; f1.u[1] = W[5]; f1.u[2] = W[6]; f1.u[3] = W[7];
#endif

    __builtin_amdgcn_s_setprio(1);
    o0 = mfma32(vc0, f0.v, o0);
    o0 = mfma32(vc1, f1.v, o0);
    o1 = mfma32(vc2, f0.v, o1);
    o1 = mfma32(vc3, f1.v, o1);
    __builtin_amdgcn_s_setprio(0);
  };

  int kb = 0;
  for (;;) {
    step(kA, kB, kb);
    kb += 32; if (kb > q0) break;
    step(kB, kA, kb);
    kb += 32; if (kb > q0) break;
  }

  const float inv = 1.0f / lr;
  const int b = bh >> 4, hh = bh & 15;
  const int q = q0 + l31;
  u16* orow = AO + (size_t)(b * 2048 + q) * 1024 + hh * 64;
#pragma unroll
  for (int r = 0; r < 16; r += 2) {
    const int dh = (r & 3) + 8 * (r >> 2) + 4 * h;   // r even -> pairs (dh, dh+1)
    *(u32*)(orow + dh)      = cvtpk(o0[r] * inv, o0[r + 1] * inv);
    *(u32*)(orow + 32 + dh) = cvtpk(o1[r] * inv, o1[r + 1] * inv);
  }
}

extern "C" void kernel_launch(void* const* d_in, const int* in_sizes, int n_in,
                              void* d_out, int out_size, void* d_ws, size_t ws_size,
                              hipStream_t stream) {
  const float* x  = (const float*)d_in[0];
  const float* wq = (const float*)d_in[1];
  const float* bq = (const float*)d_in[2];
  const float* wk = (const float*)d_in[3];
  const float* bk = (const float*)d_in[4];
  const float* wv = (const float*)d_in[5];
  const float* bv = (const float*)d_in[6];
  const float* wo = (const float*)d_in[7];
  const float* bo = (const float*)d_in[8];

  char* p = (char*)d_ws;
  u16* xb    = (u16*)p;   p += 16777216;   // 8192x1024 bf16; reused as AO after GEMM1
  u16* Wqkv  = (u16*)p;   p += 6291456;    // 3072x1024 bf16
  u16* Wo    = (u16*)p;   p += 2097152;    // 1024x1024 bf16
  float* bqkv = (float*)p; p += 12288;     // 3072 fp32
  u16* Qs    = (u16*)p;   p += 16777216;   // (B,H,T,Dh) bf16, pre-scaled by log2e/8
  u16* Ks    = (u16*)p;   p += 16777216;   // (B,H,T,Dh) bf16
  u16* Vts   = (u16*)p;   p += 16777216;   // (B,H,Dh,T) bf16
  u16* AO    = xb;                         // attention output (B,T,H*Dh) bf16 — aliases xb

  pack_w<<<16396, 256, 0, stream>>>(wq, wk, wv, wo, bq, bk, bv, Wqkv, Wo, bqkv);
  cvt_x<<<8192, 256, 0, stream>>>((const float4*)x, xb);
  gemm_bt<0><<<dim3(24, 64), 256, 0, stream>>>(xb, Wqkv, bqkv, nullptr, Qs, Ks, Vts, 1024);
  attn32<<<dim3(64, 64), 64, 0, stream>>>(Qs, Ks, Vts, AO);
  gemm_bt<1><<<dim3(8, 64), 256, 0, stream>>>(AO, Wo, bo, (float*)d_out,
                                              nullptr, nullptr, nullptr, 1024);
}